// Round 2
// baseline (840.933 us; speedup 1.0000x reference)
//
#include <hip/hip_runtime.h>

#define D 512

typedef __bf16 bf16x8 __attribute__((ext_vector_type(8)));
typedef float f32x4 __attribute__((ext_vector_type(4)));

__device__ __forceinline__ unsigned short f2bf(float f){
  union { float f; unsigned u; } v; v.f = f;
  unsigned r = v.u + 0x7fffu + ((v.u >> 16) & 1u);
  return (unsigned short)(r >> 16);
}
__device__ __forceinline__ float bf2f(unsigned h){
  union { unsigned u; float f; } v; v.u = h << 16; return v.f;
}

// ---------------- f32 -> bf16 convert ----------------
__global__ void k_f2b(const float* __restrict__ in, unsigned short* __restrict__ out, int n){
  int i = blockIdx.x*blockDim.x + threadIdx.x;
  if (i < n) out[i] = f2bf(in[i]);
}

// ---------------- gather rows a[idx]-b[idx] -> bf16 ----------------
__global__ __launch_bounds__(256) void k_gather_sub_bf16(
    const float* __restrict__ a, const float* __restrict__ b,
    const int* __restrict__ idx, unsigned short* __restrict__ out, int nrows)
{
  int g = blockIdx.x*256 + threadIdx.x;
  int total = nrows << 7;            // nrows * 128 threads (4 cols each)
  if (g >= total) return;
  int row = g >> 7, q = (g & 127) << 2;
  int s = idx[row];
  float4 va = *(const float4*)(a + (size_t)s*D + q);
  float4 vb = *(const float4*)(b + (size_t)s*D + q);
  ushort4 r;
  r.x = f2bf(va.x - vb.x); r.y = f2bf(va.y - vb.y);
  r.z = f2bf(va.z - vb.z); r.w = f2bf(va.w - vb.w);
  *(ushort4*)(out + (size_t)row*D + q) = r;
}

// ---------------- CSR build: counts (all 4 adjs in one launch) ----------------
__global__ void k_count4(const int* __restrict__ r0, int n0, int* c0,
                         const int* __restrict__ r1, int n1, int* c1,
                         const int* __restrict__ r2, int n2, int* c2,
                         const int* __restrict__ r3, int n3, int* c3)
{
  int i = blockIdx.x*blockDim.x + threadIdx.x;
  if (i < n0){ atomicAdd(&c0[r0[i]], 1); return; }
  i -= n0;
  if (i < n1){ atomicAdd(&c1[r1[i]], 1); return; }
  i -= n1;
  if (i < n2){ atomicAdd(&c2[r2[i]], 1); return; }
  i -= n2;
  if (i < n3){ atomicAdd(&c3[r3[i]], 1); }
}

__global__ __launch_bounds__(1024) void k_exscan4(
    const int* c0, int* r0, int n0,
    const int* c1, int* r1, int n1,
    const int* c2, int* r2, int n2,
    const int* c3, int* r3, int n3)
{
  __shared__ int part[1024];
  const int* cnt; int* rp; int n;
  switch (blockIdx.x){
    case 0: cnt=c0; rp=r0; n=n0; break;
    case 1: cnt=c1; rp=r1; n=n1; break;
    case 2: cnt=c2; rp=r2; n=n2; break;
    default: cnt=c3; rp=r3; n=n3; break;
  }
  int t = threadIdx.x;
  int chunk = n >> 10;               // n divisible by 1024
  int base = t*chunk;
  int s = 0;
  for (int i=0;i<chunk;i++) s += cnt[base+i];
  part[t] = s; __syncthreads();
  for (int off=1; off<1024; off<<=1){
    int v = (t>=off) ? part[t-off] : 0;
    __syncthreads();
    part[t] += v;
    __syncthreads();
  }
  int run = (t==0) ? 0 : part[t-1];
  for (int i=0;i<chunk;i++){ rp[base+i] = run; run += cnt[base+i]; }
  if (t == 1023) rp[n] = run;
}

// fill: (col,val) packed int2; optional remap col -> remap[col] (folds hist gather index)
__device__ __forceinline__ void fill_one(
    int e, const int* __restrict__ rows, const int* __restrict__ cols,
    const float* __restrict__ vals, const int* __restrict__ remap,
    const int* __restrict__ rp, int* __restrict__ fill, int2* __restrict__ bce)
{
  int r = rows[e];
  int p = atomicAdd(&fill[r], 1);
  int c = cols[e];
  if (remap) c = remap[c];
  bce[rp[r] + p] = make_int2(c, __float_as_int(vals[e]));
}

__global__ void k_fill4(
    const int* r0, const int* c0, const float* v0, const int* m0, const int* rp0, int* f0, int2* b0, int n0,
    const int* r1, const int* c1, const float* v1, const int* m1, const int* rp1, int* f1, int2* b1, int n1,
    const int* r2, const int* c2, const float* v2, const int* m2, const int* rp2, int* f2, int2* b2, int n2,
    const int* r3, const int* c3, const float* v3, const int* m3, const int* rp3, int* f3, int2* b3, int n3)
{
  int i = blockIdx.x*blockDim.x + threadIdx.x;
  if (i < n0){ fill_one(i, r0, c0, v0, m0, rp0, f0, b0); return; }
  i -= n0;
  if (i < n1){ fill_one(i, r1, c1, v1, m1, rp1, f1, b1); return; }
  i -= n1;
  if (i < n2){ fill_one(i, r2, c2, v2, m2, rp2, f2, b2); return; }
  i -= n2;
  if (i < n3){ fill_one(i, r3, c3, v3, m3, rp3, f3, b3); }
}

// ---------------- SpMM s-phase: out[row,:] = sum v * H_bf16[col,:]  (init write) ----------------
__global__ __launch_bounds__(256) void k_spmm_s(
    const int* __restrict__ rp, const int2* __restrict__ bce,
    const unsigned short* __restrict__ H, unsigned short* __restrict__ out)
{
  int row = blockIdx.x, t = threadIdx.x;
  int c = t << 1;
  float a0 = 0.f, a1 = 0.f;
  int j = rp[row], je = rp[row+1];
  for (; j + 4 <= je; j += 4){
    int2 e0=bce[j], e1=bce[j+1], e2=bce[j+2], e3=bce[j+3];
    unsigned p0 = *(const unsigned*)(H + (size_t)e0.x*D + c);
    unsigned p1 = *(const unsigned*)(H + (size_t)e1.x*D + c);
    unsigned p2 = *(const unsigned*)(H + (size_t)e2.x*D + c);
    unsigned p3 = *(const unsigned*)(H + (size_t)e3.x*D + c);
    float v0=__int_as_float(e0.y), v1=__int_as_float(e1.y),
          v2=__int_as_float(e2.y), v3=__int_as_float(e3.y);
    a0 += v0*bf2f(p0&0xffffu) + v1*bf2f(p1&0xffffu) + v2*bf2f(p2&0xffffu) + v3*bf2f(p3&0xffffu);
    a1 += v0*bf2f(p0>>16)     + v1*bf2f(p1>>16)     + v2*bf2f(p2>>16)     + v3*bf2f(p3>>16);
  }
  for (; j < je; j++){
    int2 e = bce[j]; float v = __int_as_float(e.y);
    unsigned p = *(const unsigned*)(H + (size_t)e.x*D + c);
    a0 += v*bf2f(p&0xffffu); a1 += v*bf2f(p>>16);
  }
  unsigned o = (unsigned)f2bf(a0) | ((unsigned)f2bf(a1) << 16);
  *(unsigned*)(out + (size_t)row*D + c) = o;
}

// ---------------- SpMM f-phase: out[row,:] += sum v * T_f32[col,:]  (in-place, cols pre-remapped) ----------------
__global__ __launch_bounds__(256) void k_spmm_f(
    const int* __restrict__ rp, const int2* __restrict__ bce,
    const float* __restrict__ T, unsigned short* __restrict__ out)
{
  int row = blockIdx.x, t = threadIdx.x;
  int c = t << 1;
  float a0, a1;
  {
    unsigned p = *(const unsigned*)(out + (size_t)row*D + c);
    a0 = bf2f(p&0xffffu); a1 = bf2f(p>>16);
  }
  int j = rp[row], je = rp[row+1];
  for (; j + 4 <= je; j += 4){
    int2 e0=bce[j], e1=bce[j+1], e2=bce[j+2], e3=bce[j+3];
    float2 p0 = *(const float2*)(T + (size_t)e0.x*D + c);
    float2 p1 = *(const float2*)(T + (size_t)e1.x*D + c);
    float2 p2 = *(const float2*)(T + (size_t)e2.x*D + c);
    float2 p3 = *(const float2*)(T + (size_t)e3.x*D + c);
    float v0=__int_as_float(e0.y), v1=__int_as_float(e1.y),
          v2=__int_as_float(e2.y), v3=__int_as_float(e3.y);
    a0 += v0*p0.x + v1*p1.x + v2*p2.x + v3*p3.x;
    a1 += v0*p0.y + v1*p1.y + v2*p2.y + v3*p3.y;
  }
  for (; j < je; j++){
    int2 e = bce[j]; float v = __int_as_float(e.y);
    float2 p = *(const float2*)(T + (size_t)e.x*D + c);
    a0 += v*p.x; a1 += v*p.y;
  }
  unsigned o = (unsigned)f2bf(a0) | ((unsigned)f2bf(a1) << 16);
  *(unsigned*)(out + (size_t)row*D + c) = o;
}

// ---------------- bf16 MFMA GEMM: C[M,512] = A[M,512] @ B[512,512]^T + bias ----------------
__device__ __forceinline__ void gload16(const unsigned short* g, unsigned short* l){
  __builtin_amdgcn_global_load_lds(
      (const __attribute__((address_space(1))) unsigned int*)(const void*)g,
      (__attribute__((address_space(3))) unsigned int*)(void*)l,
      16, 0, 0);
}

__global__ __launch_bounds__(256) void k_gemm_bias(
    const unsigned short* __restrict__ A,   // [M,512] bf16
    const unsigned short* __restrict__ B,   // [512,512] bf16, B[n,k]
    const float* __restrict__ bias,         // [512]
    float* __restrict__ C,                  // [M,512]
    int M)
{
  __shared__ unsigned short Al[128*32];
  __shared__ unsigned short Bl[128*32];
  int bx = blockIdx.x & 3, by = blockIdx.x >> 2;
  int m0 = by << 7, n0 = bx << 7;
  int t = threadIdx.x, wave = t >> 6, lane = t & 63;
  int wr = wave >> 1, wc = wave & 1;        // 2x2 waves, each owns 64x64
  f32x4 acc[4][4] = {};
  int flat = t << 3;
  int r0 = flat >> 5, cc = flat & 31;
  const unsigned short* pa = A + (size_t)(m0 + r0)*D + cc;
  const unsigned short* pb = B + (size_t)(n0 + r0)*D + cc;
  for (int k0 = 0; k0 < D; k0 += 32){
    gload16(pa + k0,                 &Al[flat]);
    gload16(pa + (size_t)64*D + k0,  &Al[flat + 2048]);
    gload16(pb + k0,                 &Bl[flat]);
    gload16(pb + (size_t)64*D + k0,  &Bl[flat + 2048]);
    __syncthreads();
    int arow = (wr << 6) | (lane & 15);
    int brow = (wc << 6) | (lane & 15);
    int kg   = (lane >> 4) << 3;
    bf16x8 af[4], bfr[4];
    #pragma unroll
    for (int mi=0; mi<4; mi++) af[mi]  = *(const bf16x8*)&Al[(arow + (mi<<4))*32 + kg];
    #pragma unroll
    for (int ni=0; ni<4; ni++) bfr[ni] = *(const bf16x8*)&Bl[(brow + (ni<<4))*32 + kg];
    #pragma unroll
    for (int mi=0; mi<4; mi++)
      #pragma unroll
      for (int ni=0; ni<4; ni++)
        acc[mi][ni] = __builtin_amdgcn_mfma_f32_16x16x32_bf16(af[mi], bfr[ni], acc[mi][ni], 0, 0, 0);
    __syncthreads();
  }
  int crow = m0 + (wr << 6) + ((lane >> 4) << 2);
  int ccol = n0 + (wc << 6) + (lane & 15);
  #pragma unroll
  for (int mi=0; mi<4; mi++){
    #pragma unroll
    for (int q=0; q<4; q++){
      int row = crow + (mi << 4) + q;
      float* cp = C + (size_t)row*D + ccol;
      #pragma unroll
      for (int ni=0; ni<4; ni++)
        cp[ni << 4] = acc[mi][ni][q] + bias[ccol + (ni << 4)];
    }
  }
}

// ---------------- LayerNorm + ReLU + subtract hist1[sid1] -> bf16 ----------------
__global__ __launch_bounds__(256) void k_ln_relu_sub(
    const float* __restrict__ y, const float* __restrict__ gam, const float* __restrict__ bet,
    const float* __restrict__ hist1, const int* __restrict__ sid1,
    unsigned short* __restrict__ out)
{
  __shared__ float sh[8];
  int row = blockIdx.x, t = threadIdx.x;
  int c = t << 1;
  float2 v = *(const float2*)(y + (size_t)row*D + c);
  float s = v.x + v.y, ss = v.x*v.x + v.y*v.y;
  #pragma unroll
  for (int m=1; m<64; m<<=1){ s += __shfl_xor(s, m); ss += __shfl_xor(ss, m); }
  int wave = t >> 6, lane = t & 63;
  if (lane == 0){ sh[wave] = s; sh[4+wave] = ss; }
  __syncthreads();
  s  = sh[0]+sh[1]+sh[2]+sh[3];
  ss = sh[4]+sh[5]+sh[6]+sh[7];
  float mu  = s * (1.f/D);
  float var = ss * (1.f/D) - mu*mu;
  float rr  = rsqrtf(var + 1e-5f);
  int srow = sid1[row];
  float2 hv = *(const float2*)(hist1 + (size_t)srow*D + c);
  float o0 = fmaxf((v.x - mu)*rr*gam[c]   + bet[c],   0.f) - hv.x;
  float o1 = fmaxf((v.y - mu)*rr*gam[c+1] + bet[c+1], 0.f) - hv.y;
  *(unsigned*)(out + (size_t)row*D + c) = (unsigned)f2bf(o0) | ((unsigned)f2bf(o1) << 16);
}

// ---------------- log_softmax rows ----------------
__global__ __launch_bounds__(256) void k_logsoftmax(const float* __restrict__ y, float* __restrict__ out){
  __shared__ float sh[8];
  int row = blockIdx.x, t = threadIdx.x;
  int c = t << 1;
  float2 v = *(const float2*)(y + (size_t)row*D + c);
  float m = fmaxf(v.x, v.y);
  #pragma unroll
  for (int k=1; k<64; k<<=1) m = fmaxf(m, __shfl_xor(m, k));
  int wave = t >> 6, lane = t & 63;
  if (lane == 0) sh[wave] = m;
  __syncthreads();
  m = fmaxf(fmaxf(sh[0], sh[1]), fmaxf(sh[2], sh[3]));
  __syncthreads();
  float e = expf(v.x - m) + expf(v.y - m);
  #pragma unroll
  for (int k=1; k<64; k<<=1) e += __shfl_xor(e, k);
  if (lane == 0) sh[4+wave] = e;
  __syncthreads();
  e = sh[4]+sh[5]+sh[6]+sh[7];
  float lse = m + logf(e);
  float2 o; o.x = v.x - lse; o.y = v.y - lse;
  *(float2*)(out + (size_t)row*D + c) = o;
}

extern "C" void kernel_launch(void* const* d_in, const int* in_sizes, int n_in,
                              void* d_out, int out_size, void* d_ws, size_t ws_size,
                              hipStream_t stream)
{
  const float* x     = (const float*)d_in[0];
  const float* hist0 = (const float*)d_in[1];
  const float* hist1 = (const float*)d_in[2];
  const float* w0    = (const float*)d_in[3];
  const float* b0    = (const float*)d_in[4];
  const float* g0    = (const float*)d_in[5];
  const float* beta0 = (const float*)d_in[6];
  const float* w1    = (const float*)d_in[7];
  const float* b1    = (const float*)d_in[8];
  const float* s0v   = (const float*)d_in[9];
  const float* s1v   = (const float*)d_in[10];
  const float* f0v   = (const float*)d_in[11];
  const float* f1v   = (const float*)d_in[12];
  const int* sid0    = (const int*)d_in[13];
  const int* sid1    = (const int*)d_in[14];
  const int* fid0    = (const int*)d_in[16];
  const int* fid1    = (const int*)d_in[17];
  const int* s0r     = (const int*)d_in[18];
  const int* s0c     = (const int*)d_in[19];
  const int* s1r     = (const int*)d_in[20];
  const int* s1c     = (const int*)d_in[21];
  const int* f0r     = (const int*)d_in[22];
  const int* f0c     = (const int*)d_in[23];
  const int* f1r     = (const int*)d_in[24];
  const int* f1c     = (const int*)d_in[25];

  const int N0 = 131072, N1 = 32768, N2 = 8192;
  const int Es0 = 262144, Es1 = 65536, Ef0 = 1048576, Ef1 = 262144;

  char* ws = (char*)d_ws;
  size_t off = 0;
  auto alloc = [&](size_t bytes)->char*{
    char* p = ws + off; off += (bytes + 255) & ~(size_t)255; return p;
  };
  char* regA = alloc((size_t)N0*D*2);    // 128MB: h0 -> later y1 (64MB @0) + y2 (16MB @+64MB)
  char* regB = alloc((size_t)N1*D*2);    // 32MB : h1
  char* regC = alloc((size_t)N1*D*2);    // 32MB : out1 -> later out2
  unsigned short* w0b = (unsigned short*)alloc((size_t)D*D*2);
  unsigned short* w1b = (unsigned short*)alloc((size_t)D*D*2);
  int* meta = (int*)alloc((size_t)(2*N1 + 2*N1 + 2*N2 + 2*N2)*4);
  int* cnt_s0 = meta;            int* fill_s0 = cnt_s0 + N1;
  int* cnt_f0 = fill_s0 + N1;    int* fill_f0 = cnt_f0 + N1;
  int* cnt_s1 = fill_f0 + N1;    int* fill_s1 = cnt_s1 + N2;
  int* cnt_f1 = fill_s1 + N2;    int* fill_f1 = cnt_f1 + N2;
  size_t metaBytes = (size_t)(4*N1 + 4*N2)*4;
  int* rp_s0 = (int*)alloc((size_t)(N1+1)*4);
  int* rp_f0 = (int*)alloc((size_t)(N1+1)*4);
  int* rp_s1 = (int*)alloc((size_t)(N2+1)*4);
  int* rp_f1 = (int*)alloc((size_t)(N2+1)*4);
  int2* bce_s0 = (int2*)alloc((size_t)Es0*8);
  int2* bce_f0 = (int2*)alloc((size_t)Ef0*8);
  int2* bce_s1 = (int2*)alloc((size_t)Es1*8);
  int2* bce_f1 = (int2*)alloc((size_t)Ef1*8);

  unsigned short* h0   = (unsigned short*)regA;
  unsigned short* h1   = (unsigned short*)regB;
  unsigned short* out1 = (unsigned short*)regC;
  unsigned short* out2 = (unsigned short*)regC;     // after gemm0 (out1 dead)
  float*          y1   = (float*)regA;              // after spmm_s0 (h0 dead)
  float*          y2   = (float*)(regA + ((size_t)64<<20));
  float*          outp = (float*)d_out;

  hipMemsetAsync(meta, 0, metaBytes, stream);
  k_f2b<<<(D*D + 255)/256, 256, 0, stream>>>(w0, w0b, D*D);
  k_f2b<<<(D*D + 255)/256, 256, 0, stream>>>(w1, w1b, D*D);
  // h0 = x[sid0] - hist0[sid0]  (bf16)
  k_gather_sub_bf16<<<N0*128/256, 256, 0, stream>>>(x, hist0, sid0, h0, N0);
  // CSR build (f-adj cols remapped through fid -> hist row ids)
  const int Etot = Es0 + Ef0 + Es1 + Ef1;
  k_count4<<<Etot/256, 256, 0, stream>>>(s0r, Es0, cnt_s0, f0r, Ef0, cnt_f0,
                                         s1r, Es1, cnt_s1, f1r, Ef1, cnt_f1);
  k_exscan4<<<4, 1024, 0, stream>>>(cnt_s0, rp_s0, N1, cnt_f0, rp_f0, N1,
                                    cnt_s1, rp_s1, N2, cnt_f1, rp_f1, N2);
  k_fill4<<<Etot/256, 256, 0, stream>>>(
      s0r, s0c, s0v, nullptr, rp_s0, fill_s0, bce_s0, Es0,
      f0r, f0c, f0v, fid0,    rp_f0, fill_f0, bce_f0, Ef0,
      s1r, s1c, s1v, nullptr, rp_s1, fill_s1, bce_s1, Es1,
      f1r, f1c, f1v, fid1,    rp_f1, fill_f1, bce_f1, Ef1);
  // layer 0
  k_spmm_s<<<N1, 256, 0, stream>>>(rp_s0, bce_s0, h0, out1);
  k_spmm_f<<<N1, 256, 0, stream>>>(rp_f0, bce_f0, hist0, out1);
  k_gemm_bias<<<(N1/128)*4, 256, 0, stream>>>(out1, w0b, b0, y1, N1);
  k_ln_relu_sub<<<N1, 256, 0, stream>>>(y1, g0, beta0, hist1, sid1, h1);
  // layer 1
  k_spmm_s<<<N2, 256, 0, stream>>>(rp_s1, bce_s1, h1, out2);
  k_spmm_f<<<N2, 256, 0, stream>>>(rp_f1, bce_f1, hist1, out2);
  k_gemm_bias<<<(N2/128)*4, 256, 0, stream>>>(out2, w1b, b1, y2, N2);
  k_logsoftmax<<<N2, 256, 0, stream>>>(y2, outp);
}

// Round 3
// 715.555 us; speedup vs baseline: 1.1752x; 1.1752x over previous
//
#include <hip/hip_runtime.h>

#define D 512

typedef __bf16 bf16x8 __attribute__((ext_vector_type(8)));
typedef float f32x4 __attribute__((ext_vector_type(4)));

__device__ __forceinline__ unsigned short f2bf(float f){
  union { float f; unsigned u; } v; v.f = f;
  unsigned r = v.u + 0x7fffu + ((v.u >> 16) & 1u);
  return (unsigned short)(r >> 16);
}
__device__ __forceinline__ float bf2f(unsigned h){
  union { unsigned u; float f; } v; v.u = h << 16; return v.f;
}

// ---------------- f32 -> bf16 convert, scalar (small n) ----------------
__global__ void k_f2b(const float* __restrict__ in, unsigned short* __restrict__ out, int n){
  int i = blockIdx.x*blockDim.x + threadIdx.x;
  if (i < n) out[i] = f2bf(in[i]);
}

// ---------------- f32 -> bf16 convert, vectorized x4 (n % 4 == 0) ----------------
__global__ __launch_bounds__(256) void k_f2b4(const float* __restrict__ in, unsigned short* __restrict__ out, int n4){
  int i = blockIdx.x*256 + threadIdx.x;
  if (i >= n4) return;
  float4 v = *(const float4*)(in + (size_t)i*4);
  ushort4 r;
  r.x = f2bf(v.x); r.y = f2bf(v.y); r.z = f2bf(v.z); r.w = f2bf(v.w);
  *(ushort4*)(out + (size_t)i*4) = r;
}

// ---------------- h0 = f32 a[idx] - bf16 Hb[idx] -> bf16 ----------------
__global__ __launch_bounds__(256) void k_gather_sub_mixed(
    const float* __restrict__ a, const unsigned short* __restrict__ Hb,
    const int* __restrict__ idx, unsigned short* __restrict__ out, int nrows)
{
  int g = blockIdx.x*256 + threadIdx.x;
  int total = nrows << 7;            // 128 threads/row, 4 cols each
  if (g >= total) return;
  int row = g >> 7, q = (g & 127) << 2;
  int s = idx[row];
  float4 va = *(const float4*)(a + (size_t)s*D + q);
  ushort4 hb = *(const ushort4*)(Hb + (size_t)s*D + q);
  ushort4 r;
  r.x = f2bf(va.x - bf2f(hb.x)); r.y = f2bf(va.y - bf2f(hb.y));
  r.z = f2bf(va.z - bf2f(hb.z)); r.w = f2bf(va.w - bf2f(hb.w));
  *(ushort4*)(out + (size_t)row*D + q) = r;
}

// ---------------- out[row] = bf16(T_f32[idx[row]]) ----------------
__global__ __launch_bounds__(256) void k_gather1_bf16(
    const float* __restrict__ T, const int* __restrict__ idx,
    unsigned short* __restrict__ out, int nrows)
{
  int g = blockIdx.x*256 + threadIdx.x;
  int total = nrows << 7;
  if (g >= total) return;
  int row = g >> 7, q = (g & 127) << 2;
  int s = idx[row];
  float4 v = *(const float4*)(T + (size_t)s*D + q);
  ushort4 r;
  r.x = f2bf(v.x); r.y = f2bf(v.y); r.z = f2bf(v.z); r.w = f2bf(v.w);
  *(ushort4*)(out + (size_t)row*D + q) = r;
}

// ---------------- CSR build ----------------
__global__ void k_count4(const int* __restrict__ r0, int n0, int* c0,
                         const int* __restrict__ r1, int n1, int* c1,
                         const int* __restrict__ r2, int n2, int* c2,
                         const int* __restrict__ r3, int n3, int* c3)
{
  int i = blockIdx.x*blockDim.x + threadIdx.x;
  if (i < n0){ atomicAdd(&c0[r0[i]], 1); return; }
  i -= n0;
  if (i < n1){ atomicAdd(&c1[r1[i]], 1); return; }
  i -= n1;
  if (i < n2){ atomicAdd(&c2[r2[i]], 1); return; }
  i -= n2;
  if (i < n3){ atomicAdd(&c3[r3[i]], 1); }
}

__global__ __launch_bounds__(1024) void k_exscan4(
    const int* c0, int* r0, int n0,
    const int* c1, int* r1, int n1,
    const int* c2, int* r2, int n2,
    const int* c3, int* r3, int n3)
{
  __shared__ int part[1024];
  const int* cnt; int* rp; int n;
  switch (blockIdx.x){
    case 0: cnt=c0; rp=r0; n=n0; break;
    case 1: cnt=c1; rp=r1; n=n1; break;
    case 2: cnt=c2; rp=r2; n=n2; break;
    default: cnt=c3; rp=r3; n=n3; break;
  }
  int t = threadIdx.x;
  int chunk = n >> 10;
  int base = t*chunk;
  int s = 0;
  for (int i=0;i<chunk;i++) s += cnt[base+i];
  part[t] = s; __syncthreads();
  for (int off=1; off<1024; off<<=1){
    int v = (t>=off) ? part[t-off] : 0;
    __syncthreads();
    part[t] += v;
    __syncthreads();
  }
  int run = (t==0) ? 0 : part[t-1];
  for (int i=0;i<chunk;i++){ rp[base+i] = run; run += cnt[base+i]; }
  if (t == 1023) rp[n] = run;
}

__device__ __forceinline__ void fill_one(
    int e, const int* __restrict__ rows, const int* __restrict__ cols,
    const float* __restrict__ vals, const int* __restrict__ remap,
    const int* __restrict__ rp, int* __restrict__ fill, int2* __restrict__ bce)
{
  int r = rows[e];
  int p = atomicAdd(&fill[r], 1);
  int c = cols[e];
  if (remap) c = remap[c];
  bce[rp[r] + p] = make_int2(c, __float_as_int(vals[e]));
}

__global__ void k_fill4(
    const int* r0, const int* c0, const float* v0, const int* m0, const int* rp0, int* f0, int2* b0, int n0,
    const int* r1, const int* c1, const float* v1, const int* m1, const int* rp1, int* f1, int2* b1, int n1,
    const int* r2, const int* c2, const float* v2, const int* m2, const int* rp2, int* f2, int2* b2, int n2,
    const int* r3, const int* c3, const float* v3, const int* m3, const int* rp3, int* f3, int2* b3, int n3)
{
  int i = blockIdx.x*blockDim.x + threadIdx.x;
  if (i < n0){ fill_one(i, r0, c0, v0, m0, rp0, f0, b0); return; }
  i -= n0;
  if (i < n1){ fill_one(i, r1, c1, v1, m1, rp1, f1, b1); return; }
  i -= n1;
  if (i < n2){ fill_one(i, r2, c2, v2, m2, rp2, f2, b2); return; }
  i -= n2;
  if (i < n3){ fill_one(i, r3, c3, v3, m3, rp3, f3, b3); }
}

// ---------------- SpMM over bf16 table: INIT writes, ACC accumulates in-place ----------------
template<bool ACC>
__device__ __forceinline__ void spmm_body(
    const int* __restrict__ rp, const int2* __restrict__ bce,
    const unsigned short* __restrict__ H, unsigned short* __restrict__ out)
{
  int row = blockIdx.x, t = threadIdx.x;
  int c = t << 1;
  float a0, a1;
  if (ACC){
    unsigned p = *(const unsigned*)(out + (size_t)row*D + c);
    a0 = bf2f(p & 0xffffu); a1 = bf2f(p >> 16);
  } else {
    a0 = 0.f; a1 = 0.f;
  }
  int j = rp[row], je = rp[row+1];
  for (; j + 8 <= je; j += 8){
    int2 e[8]; unsigned p[8];
    #pragma unroll
    for (int u=0; u<8; u++) e[u] = bce[j+u];
    #pragma unroll
    for (int u=0; u<8; u++) p[u] = *(const unsigned*)(H + (size_t)e[u].x*D + c);
    #pragma unroll
    for (int u=0; u<8; u++){
      float v = __int_as_float(e[u].y);
      a0 += v*bf2f(p[u] & 0xffffu);
      a1 += v*bf2f(p[u] >> 16);
    }
  }
  if (j + 4 <= je){
    int2 e[4]; unsigned p[4];
    #pragma unroll
    for (int u=0; u<4; u++) e[u] = bce[j+u];
    #pragma unroll
    for (int u=0; u<4; u++) p[u] = *(const unsigned*)(H + (size_t)e[u].x*D + c);
    #pragma unroll
    for (int u=0; u<4; u++){
      float v = __int_as_float(e[u].y);
      a0 += v*bf2f(p[u] & 0xffffu);
      a1 += v*bf2f(p[u] >> 16);
    }
    j += 4;
  }
  for (; j < je; j++){
    int2 e = bce[j]; float v = __int_as_float(e.y);
    unsigned p = *(const unsigned*)(H + (size_t)e.x*D + c);
    a0 += v*bf2f(p & 0xffffu); a1 += v*bf2f(p >> 16);
  }
  unsigned o = (unsigned)f2bf(a0) | ((unsigned)f2bf(a1) << 16);
  *(unsigned*)(out + (size_t)row*D + c) = o;
}

__global__ __launch_bounds__(256) void k_spmm_init(
    const int* __restrict__ rp, const int2* __restrict__ bce,
    const unsigned short* __restrict__ H, unsigned short* __restrict__ out)
{ spmm_body<false>(rp, bce, H, out); }

__global__ __launch_bounds__(256) void k_spmm_acc(
    const int* __restrict__ rp, const int2* __restrict__ bce,
    const unsigned short* __restrict__ H, unsigned short* __restrict__ out)
{ spmm_body<true>(rp, bce, H, out); }

// ---------------- bf16 MFMA GEMM: C[M,512] = A[M,512] @ B[512,512]^T + bias ----------------
__device__ __forceinline__ void gload16(const unsigned short* g, unsigned short* l){
  __builtin_amdgcn_global_load_lds(
      (const __attribute__((address_space(1))) unsigned int*)(const void*)g,
      (__attribute__((address_space(3))) unsigned int*)(void*)l,
      16, 0, 0);
}

__global__ __launch_bounds__(256) void k_gemm_bias(
    const unsigned short* __restrict__ A,
    const unsigned short* __restrict__ B,
    const float* __restrict__ bias,
    float* __restrict__ C,
    int M)
{
  __shared__ unsigned short Al[128*32];
  __shared__ unsigned short Bl[128*32];
  int bx = blockIdx.x & 3, by = blockIdx.x >> 2;
  int m0 = by << 7, n0 = bx << 7;
  int t = threadIdx.x, wave = t >> 6, lane = t & 63;
  int wr = wave >> 1, wc = wave & 1;
  f32x4 acc[4][4] = {};
  int flat = t << 3;
  int r0 = flat >> 5, cc = flat & 31;
  const unsigned short* pa = A + (size_t)(m0 + r0)*D + cc;
  const unsigned short* pb = B + (size_t)(n0 + r0)*D + cc;
  for (int k0 = 0; k0 < D; k0 += 32){
    gload16(pa + k0,                 &Al[flat]);
    gload16(pa + (size_t)64*D + k0,  &Al[flat + 2048]);
    gload16(pb + k0,                 &Bl[flat]);
    gload16(pb + (size_t)64*D + k0,  &Bl[flat + 2048]);
    __syncthreads();
    int arow = (wr << 6) | (lane & 15);
    int brow = (wc << 6) | (lane & 15);
    int kg   = (lane >> 4) << 3;
    bf16x8 af[4], bfr[4];
    #pragma unroll
    for (int mi=0; mi<4; mi++) af[mi]  = *(const bf16x8*)&Al[(arow + (mi<<4))*32 + kg];
    #pragma unroll
    for (int ni=0; ni<4; ni++) bfr[ni] = *(const bf16x8*)&Bl[(brow + (ni<<4))*32 + kg];
    #pragma unroll
    for (int mi=0; mi<4; mi++)
      #pragma unroll
      for (int ni=0; ni<4; ni++)
        acc[mi][ni] = __builtin_amdgcn_mfma_f32_16x16x32_bf16(af[mi], bfr[ni], acc[mi][ni], 0, 0, 0);
    __syncthreads();
  }
  int crow = m0 + (wr << 6) + ((lane >> 4) << 2);
  int ccol = n0 + (wc << 6) + (lane & 15);
  #pragma unroll
  for (int mi=0; mi<4; mi++){
    #pragma unroll
    for (int q=0; q<4; q++){
      int row = crow + (mi << 4) + q;
      float* cp = C + (size_t)row*D + ccol;
      #pragma unroll
      for (int ni=0; ni<4; ni++)
        cp[ni << 4] = acc[mi][ni][q] + bias[ccol + (ni << 4)];
    }
  }
}

// ---------------- LayerNorm + ReLU + subtract hist1[sid1] -> bf16 ----------------
__global__ __launch_bounds__(256) void k_ln_relu_sub(
    const float* __restrict__ y, const float* __restrict__ gam, const float* __restrict__ bet,
    const float* __restrict__ hist1, const int* __restrict__ sid1,
    unsigned short* __restrict__ out)
{
  __shared__ float sh[8];
  int row = blockIdx.x, t = threadIdx.x;
  int c = t << 1;
  float2 v = *(const float2*)(y + (size_t)row*D + c);
  float s = v.x + v.y, ss = v.x*v.x + v.y*v.y;
  #pragma unroll
  for (int m=1; m<64; m<<=1){ s += __shfl_xor(s, m); ss += __shfl_xor(ss, m); }
  int wave = t >> 6, lane = t & 63;
  if (lane == 0){ sh[wave] = s; sh[4+wave] = ss; }
  __syncthreads();
  s  = sh[0]+sh[1]+sh[2]+sh[3];
  ss = sh[4]+sh[5]+sh[6]+sh[7];
  float mu  = s * (1.f/D);
  float var = ss * (1.f/D) - mu*mu;
  float rr  = rsqrtf(var + 1e-5f);
  int srow = sid1[row];
  float2 hv = *(const float2*)(hist1 + (size_t)srow*D + c);
  float o0 = fmaxf((v.x - mu)*rr*gam[c]   + bet[c],   0.f) - hv.x;
  float o1 = fmaxf((v.y - mu)*rr*gam[c+1] + bet[c+1], 0.f) - hv.y;
  *(unsigned*)(out + (size_t)row*D + c) = (unsigned)f2bf(o0) | ((unsigned)f2bf(o1) << 16);
}

// ---------------- log_softmax rows ----------------
__global__ __launch_bounds__(256) void k_logsoftmax(const float* __restrict__ y, float* __restrict__ out){
  __shared__ float sh[8];
  int row = blockIdx.x, t = threadIdx.x;
  int c = t << 1;
  float2 v = *(const float2*)(y + (size_t)row*D + c);
  float m = fmaxf(v.x, v.y);
  #pragma unroll
  for (int k=1; k<64; k<<=1) m = fmaxf(m, __shfl_xor(m, k));
  int wave = t >> 6, lane = t & 63;
  if (lane == 0) sh[wave] = m;
  __syncthreads();
  m = fmaxf(fmaxf(sh[0], sh[1]), fmaxf(sh[2], sh[3]));
  __syncthreads();
  float e = expf(v.x - m) + expf(v.y - m);
  #pragma unroll
  for (int k=1; k<64; k<<=1) e += __shfl_xor(e, k);
  if (lane == 0) sh[4+wave] = e;
  __syncthreads();
  e = sh[4]+sh[5]+sh[6]+sh[7];
  float lse = m + logf(e);
  float2 o; o.x = v.x - lse; o.y = v.y - lse;
  *(float2*)(out + (size_t)row*D + c) = o;
}

extern "C" void kernel_launch(void* const* d_in, const int* in_sizes, int n_in,
                              void* d_out, int out_size, void* d_ws, size_t ws_size,
                              hipStream_t stream)
{
  const float* x     = (const float*)d_in[0];
  const float* hist0 = (const float*)d_in[1];
  const float* hist1 = (const float*)d_in[2];
  const float* w0    = (const float*)d_in[3];
  const float* b0    = (const float*)d_in[4];
  const float* g0    = (const float*)d_in[5];
  const float* beta0 = (const float*)d_in[6];
  const float* w1    = (const float*)d_in[7];
  const float* b1    = (const float*)d_in[8];
  const float* s0v   = (const float*)d_in[9];
  const float* s1v   = (const float*)d_in[10];
  const float* f0v   = (const float*)d_in[11];
  const float* f1v   = (const float*)d_in[12];
  const int* sid0    = (const int*)d_in[13];
  const int* sid1    = (const int*)d_in[14];
  const int* fid0    = (const int*)d_in[16];
  const int* fid1    = (const int*)d_in[17];
  const int* s0r     = (const int*)d_in[18];
  const int* s0c     = (const int*)d_in[19];
  const int* s1r     = (const int*)d_in[20];
  const int* s1c     = (const int*)d_in[21];
  const int* f0r     = (const int*)d_in[22];
  const int* f0c     = (const int*)d_in[23];
  const int* f1r     = (const int*)d_in[24];
  const int* f1c     = (const int*)d_in[25];

  const int N  = 100000;
  const int N0 = 131072, N1 = 32768, N2 = 8192;
  const int Es0 = 262144, Es1 = 65536, Ef0 = 1048576, Ef1 = 262144;

  char* ws = (char*)d_ws;
  size_t off = 0;
  auto alloc = [&](size_t bytes)->char*{
    char* p = ws + off; off += (bytes + 255) & ~(size_t)255; return p;
  };
  char* regA = alloc((size_t)N0*D*2);      // 128MiB: h0 -> y1 (64MiB @0) + y2 (16MiB @+64MiB)
  char* regH = alloc((size_t)N*D*2);       // 102MB : H0b -> g1buf (@0) + h1 (@+N1*D*2)
  char* regC = alloc((size_t)N1*D*2);      // 32MiB : out1 -> out2
  unsigned short* w0b = (unsigned short*)alloc((size_t)D*D*2);
  unsigned short* w1b = (unsigned short*)alloc((size_t)D*D*2);
  int* meta = (int*)alloc((size_t)(4*N1 + 4*N2)*4);
  int* cnt_s0 = meta;            int* fill_s0 = cnt_s0 + N1;
  int* cnt_f0 = fill_s0 + N1;    int* fill_f0 = cnt_f0 + N1;
  int* cnt_s1 = fill_f0 + N1;    int* fill_s1 = cnt_s1 + N2;
  int* cnt_f1 = fill_s1 + N2;    int* fill_f1 = cnt_f1 + N2;
  size_t metaBytes = (size_t)(4*N1 + 4*N2)*4;
  int* rp_s0 = (int*)alloc((size_t)(N1+1)*4);
  int* rp_f0 = (int*)alloc((size_t)(N1+1)*4);
  int* rp_s1 = (int*)alloc((size_t)(N2+1)*4);
  int* rp_f1 = (int*)alloc((size_t)(N2+1)*4);
  int2* bce_s0 = (int2*)alloc((size_t)Es0*8);
  int2* bce_f0 = (int2*)alloc((size_t)Ef0*8);
  int2* bce_s1 = (int2*)alloc((size_t)Es1*8);
  int2* bce_f1 = (int2*)alloc((size_t)Ef1*8);

  unsigned short* h0    = (unsigned short*)regA;
  float*          y1    = (float*)regA;                      // after spmm_s0 (h0 dead)
  float*          y2    = (float*)(regA + ((size_t)64<<20));
  unsigned short* H0b   = (unsigned short*)regH;
  unsigned short* g1buf = (unsigned short*)regH;             // after spmm_acc f0 (H0b dead)
  unsigned short* h1    = (unsigned short*)(regH + (size_t)N1*D*2);
  unsigned short* out1  = (unsigned short*)regC;
  unsigned short* out2  = (unsigned short*)regC;             // after gemm0 (out1 dead)
  float*          outp  = (float*)d_out;

  hipMemsetAsync(meta, 0, metaBytes, stream);
  k_f2b<<<(D*D + 255)/256, 256, 0, stream>>>(w0, w0b, D*D);
  k_f2b<<<(D*D + 255)/256, 256, 0, stream>>>(w1, w1b, D*D);
  // CSR build (f-adj cols remapped through fid -> history row ids for layer 0 only)
  const int Etot = Es0 + Ef0 + Es1 + Ef1;
  k_count4<<<Etot/256, 256, 0, stream>>>(s0r, Es0, cnt_s0, f0r, Ef0, cnt_f0,
                                         s1r, Es1, cnt_s1, f1r, Ef1, cnt_f1);
  k_exscan4<<<4, 1024, 0, stream>>>(cnt_s0, rp_s0, N1, cnt_f0, rp_f0, N1,
                                    cnt_s1, rp_s1, N2, cnt_f1, rp_f1, N2);
  k_fill4<<<Etot/256, 256, 0, stream>>>(
      s0r, s0c, s0v, nullptr, rp_s0, fill_s0, bce_s0, Es0,
      f0r, f0c, f0v, fid0,    rp_f0, fill_f0, bce_f0, Ef0,
      s1r, s1c, s1v, nullptr, rp_s1, fill_s1, bce_s1, Es1,
      f1r, f1c, f1v, nullptr, rp_f1, fill_f1, bce_f1, Ef1);
  // hist0 -> bf16 table (L3-resident afterwards)
  k_f2b4<<<(N*D/4 + 255)/256, 256, 0, stream>>>(hist0, H0b, N*D/4);
  // h0 = x[sid0] - H0b[sid0]  (bf16)
  k_gather_sub_mixed<<<N0*128/256, 256, 0, stream>>>(x, H0b, sid0, h0, N0);
  // layer 0 aggregation
  k_spmm_init<<<N1, 256, 0, stream>>>(rp_s0, bce_s0, h0, out1);     // s-path over h0
  k_spmm_acc <<<N1, 256, 0, stream>>>(rp_f0, bce_f0, H0b, out1);    // f-path over H0b (remapped cols)
  // layer-1 history pre-gather (H0b dead now; reuse regH)
  k_gather1_bf16<<<N1*128/256, 256, 0, stream>>>(hist1, fid1, g1buf, N1);
  // dense + norm
  k_gemm_bias<<<(N1/128)*4, 256, 0, stream>>>(out1, w0b, b0, y1, N1);
  k_ln_relu_sub<<<N1, 256, 0, stream>>>(y1, g0, beta0, hist1, sid1, h1);
  // layer 1 aggregation
  k_spmm_init<<<N2, 256, 0, stream>>>(rp_s1, bce_s1, h1, out2);
  k_spmm_acc <<<N2, 256, 0, stream>>>(rp_f1, bce_f1, g1buf, out2);
  // dense + log-softmax
  k_gemm_bias<<<(N2/128)*4, 256, 0, stream>>>(out2, w1b, b1, y2, N2);
  k_logsoftmax<<<N2, 256, 0, stream>>>(y2, outp);
}

// Round 6
// 688.068 us; speedup vs baseline: 1.2222x; 1.0399x over previous
//
#include <hip/hip_runtime.h>

#define D 512

typedef __bf16 bf16x8 __attribute__((ext_vector_type(8)));
typedef float f32x4 __attribute__((ext_vector_type(4)));

__device__ __forceinline__ unsigned f2bf(float f){
  union { float f; unsigned u; } v; v.f = f;
  unsigned r = v.u + 0x7fffu + ((v.u >> 16) & 1u);
  return r >> 16;
}
__device__ __forceinline__ float bf2f(unsigned h){
  union { unsigned u; float f; } v; v.u = h << 16; return v.f;
}

// ---------------- weights f32 -> bf16 (both tables, one launch) ----------------
__global__ void k_f2bw(const float* __restrict__ w0, const float* __restrict__ w1,
                       unsigned short* __restrict__ o0, unsigned short* __restrict__ o1){
  int i = blockIdx.x*blockDim.x + threadIdx.x;
  if (i < D*D) o0[i] = (unsigned short)f2bf(w0[i]);
  else { i -= D*D; o1[i] = (unsigned short)f2bf(w1[i]); }
}

// ---------------- f32 -> bf16 table convert, x8/thread (NT reads) ----------------
__global__ __launch_bounds__(256) void k_f2b8(const float* __restrict__ in, unsigned short* __restrict__ out, int n8){
  int i = blockIdx.x*256 + threadIdx.x;
  if (i >= n8) return;
  const f32x4* p = (const f32x4*)(in + (size_t)i*8);
  f32x4 v0 = __builtin_nontemporal_load(p);
  f32x4 v1 = __builtin_nontemporal_load(p+1);
  uint4 r;
  r.x = f2bf(v0[0]) | (f2bf(v0[1])<<16);
  r.y = f2bf(v0[2]) | (f2bf(v0[3])<<16);
  r.z = f2bf(v1[0]) | (f2bf(v1[1])<<16);
  r.w = f2bf(v1[2]) | (f2bf(v1[3])<<16);
  *(uint4*)(out + (size_t)i*8) = r;
}

// ---------------- h0 = f32 x[idx] - bf16 Hb[idx] -> bf16 ----------------
__global__ __launch_bounds__(256) void k_gather_sub_mixed(
    const float* __restrict__ x, const unsigned short* __restrict__ Hb,
    const int* __restrict__ idx, unsigned short* __restrict__ out, int nrows)
{
  int g = blockIdx.x*256 + threadIdx.x;
  if (g >= (nrows << 7)) return;
  int row = g >> 7, q = (g & 127) << 2;
  int s = idx[row];
  f32x4 xa = __builtin_nontemporal_load((const f32x4*)(x + (size_t)s*D + q));
  ushort4 hb = *(const ushort4*)(Hb + (size_t)s*D + q);
  ushort4 r;
  r.x = (unsigned short)f2bf(xa[0] - bf2f(hb.x));
  r.y = (unsigned short)f2bf(xa[1] - bf2f(hb.y));
  r.z = (unsigned short)f2bf(xa[2] - bf2f(hb.z));
  r.w = (unsigned short)f2bf(xa[3] - bf2f(hb.w));
  *(ushort4*)(out + (size_t)row*D + q) = r;
}

// ---------------- out[row] = bf16(T_f32[idx[row]]) ----------------
__global__ __launch_bounds__(256) void k_gather1_bf16(
    const float* __restrict__ T, const int* __restrict__ idx,
    unsigned short* __restrict__ out, int nrows)
{
  int g = blockIdx.x*256 + threadIdx.x;
  if (g >= (nrows << 7)) return;
  int row = g >> 7, q = (g & 127) << 2;
  int s = idx[row];
  f32x4 v = __builtin_nontemporal_load((const f32x4*)(T + (size_t)s*D + q));
  ushort4 r;
  r.x = (unsigned short)f2bf(v[0]); r.y = (unsigned short)f2bf(v[1]);
  r.z = (unsigned short)f2bf(v[2]); r.w = (unsigned short)f2bf(v[3]);
  *(ushort4*)(out + (size_t)row*D + q) = r;
}

// ---------------- CSR build ----------------
__global__ void k_count4(const int* __restrict__ r0, int n0, int* c0,
                         const int* __restrict__ r1, int n1, int* c1,
                         const int* __restrict__ r2, int n2, int* c2,
                         const int* __restrict__ r3, int n3, int* c3)
{
  int i = blockIdx.x*blockDim.x + threadIdx.x;
  if (i < n0){ atomicAdd(&c0[r0[i]], 1); return; }
  i -= n0;
  if (i < n1){ atomicAdd(&c1[r1[i]], 1); return; }
  i -= n1;
  if (i < n2){ atomicAdd(&c2[r2[i]], 1); return; }
  i -= n2;
  if (i < n3){ atomicAdd(&c3[r3[i]], 1); }
}

__global__ __launch_bounds__(1024) void k_exscan4(
    const int* c0, int* r0, int n0,
    const int* c1, int* r1, int n1,
    const int* c2, int* r2, int n2,
    const int* c3, int* r3, int n3)
{
  __shared__ int part[1024];
  const int* cnt; int* rp; int n;
  switch (blockIdx.x){
    case 0: cnt=c0; rp=r0; n=n0; break;
    case 1: cnt=c1; rp=r1; n=n1; break;
    case 2: cnt=c2; rp=r2; n=n2; break;
    default: cnt=c3; rp=r3; n=n3; break;
  }
  int t = threadIdx.x;
  int chunk = n >> 10;
  int base = t*chunk;
  int s = 0;
  for (int i=0;i<chunk;i++) s += cnt[base+i];
  part[t] = s; __syncthreads();
  for (int off=1; off<1024; off<<=1){
    int v = (t>=off) ? part[t-off] : 0;
    __syncthreads();
    part[t] += v;
    __syncthreads();
  }
  int run = (t==0) ? 0 : part[t-1];
  for (int i=0;i<chunk;i++){ rp[base+i] = run; run += cnt[base+i]; }
  if (t == 1023) rp[n] = run;
}

__device__ __forceinline__ void fill_one(
    int e, const int* __restrict__ rows, const int* __restrict__ cols,
    const float* __restrict__ vals, const int* __restrict__ remap,
    const int* __restrict__ rp, int* __restrict__ fill, int2* __restrict__ bce)
{
  int r = rows[e];
  int p = atomicAdd(&fill[r], 1);
  int c = cols[e];
  if (remap) c = remap[c];
  bce[rp[r] + p] = make_int2(c, __float_as_int(vals[e]));
}

__global__ void k_fill4(
    const int* r0, const int* c0, const float* v0, const int* m0, const int* rp0, int* f0, int2* b0, int n0,
    const int* r1, const int* c1, const float* v1, const int* m1, const int* rp1, int* f1, int2* b1, int n1,
    const int* r2, const int* c2, const float* v2, const int* m2, const int* rp2, int* f2, int2* b2, int n2,
    const int* r3, const int* c3, const float* v3, const int* m3, const int* rp3, int* f3, int2* b3, int n3)
{
  int i = blockIdx.x*blockDim.x + threadIdx.x;
  if (i < n0){ fill_one(i, r0, c0, v0, m0, rp0, f0, b0); return; }
  i -= n0;
  if (i < n1){ fill_one(i, r1, c1, v1, m1, rp1, f1, b1); return; }
  i -= n1;
  if (i < n2){ fill_one(i, r2, c2, v2, m2, rp2, f2, b2); return; }
  i -= n2;
  if (i < n3){ fill_one(i, r3, c3, v3, m3, rp3, f3, b3); }
}

// ---------------- fused dual SpMM, one WAVE per output row, bf16 tables ----------------
__device__ __forceinline__ void acc_bf16(float* a, uint4 p, float v){
  a[0] += v*bf2f(p.x & 0xffffu); a[1] += v*bf2f(p.x >> 16);
  a[2] += v*bf2f(p.y & 0xffffu); a[3] += v*bf2f(p.y >> 16);
  a[4] += v*bf2f(p.z & 0xffffu); a[5] += v*bf2f(p.z >> 16);
  a[6] += v*bf2f(p.w & 0xffffu); a[7] += v*bf2f(p.w >> 16);
}

__device__ __forceinline__ void spmm_phase(
    const int* __restrict__ rp, const int2* __restrict__ be,
    const unsigned short* __restrict__ H, int row, int lane, float* a)
{
  int j = rp[row], je = rp[row+1];
  for (; j + 8 <= je; j += 8){
    int2 e[8]; uint4 p[8];
    #pragma unroll
    for (int u=0;u<8;u++) e[u] = be[j+u];
    #pragma unroll
    for (int u=0;u<8;u++) p[u] = *(const uint4*)(H + (size_t)e[u].x*D + lane*8);
    #pragma unroll
    for (int u=0;u<8;u++) acc_bf16(a, p[u], __int_as_float(e[u].y));
  }
  if (j + 4 <= je){
    int2 e[4]; uint4 p[4];
    #pragma unroll
    for (int u=0;u<4;u++) e[u] = be[j+u];
    #pragma unroll
    for (int u=0;u<4;u++) p[u] = *(const uint4*)(H + (size_t)e[u].x*D + lane*8);
    #pragma unroll
    for (int u=0;u<4;u++) acc_bf16(a, p[u], __int_as_float(e[u].y));
    j += 4;
  }
  for (; j < je; j++){
    int2 e = be[j];
    uint4 p = *(const uint4*)(H + (size_t)e.x*D + lane*8);
    acc_bf16(a, p, __int_as_float(e.y));
  }
}

__global__ __launch_bounds__(256) void k_spmm_dual(
    const int* __restrict__ rps, const int2* __restrict__ bes, const unsigned short* __restrict__ Hs,
    const int* __restrict__ rpf, const int2* __restrict__ bef, const unsigned short* __restrict__ Hf,
    unsigned short* __restrict__ out, int nrows)
{
  int wid = threadIdx.x >> 6, lane = threadIdx.x & 63;
  int row = blockIdx.x*4 + wid;
  if (row >= nrows) return;
  float a[8] = {0.f,0.f,0.f,0.f,0.f,0.f,0.f,0.f};
  spmm_phase(rps, bes, Hs, row, lane, a);
  spmm_phase(rpf, bef, Hf, row, lane, a);
  uint4 o;
  o.x = f2bf(a[0]) | (f2bf(a[1]) << 16);
  o.y = f2bf(a[2]) | (f2bf(a[3]) << 16);
  o.z = f2bf(a[4]) | (f2bf(a[5]) << 16);
  o.w = f2bf(a[6]) | (f2bf(a[7]) << 16);
  *(uint4*)(out + (size_t)row*D + lane*8) = o;
}

// ---------------- bf16 MFMA GEMM: C[M,512] = A[M,512] @ B[512,512]^T + bias ----------------
__device__ __forceinline__ void gload16(const unsigned short* g, unsigned short* l){
  __builtin_amdgcn_global_load_lds(
      (const __attribute__((address_space(1))) unsigned int*)(const void*)g,
      (__attribute__((address_space(3))) unsigned int*)(void*)l,
      16, 0, 0);
}

template<bool OUT_BF16>
__global__ __launch_bounds__(256) void k_gemm_bias(
    const unsigned short* __restrict__ A,
    const unsigned short* __restrict__ B,
    const float* __restrict__ bias,
    void* __restrict__ Cv,
    int M)
{
  __shared__ unsigned short Al[128*32];
  __shared__ unsigned short Bl[128*32];
  int bx = blockIdx.x & 3, by = blockIdx.x >> 2;
  int m0 = by << 7, n0 = bx << 7;
  int t = threadIdx.x, wave = t >> 6, lane = t & 63;
  int wr = wave >> 1, wc = wave & 1;
  f32x4 acc[4][4] = {};
  int flat = t << 3;
  int r0 = flat >> 5, cc = flat & 31;
  const unsigned short* pa = A + (size_t)(m0 + r0)*D + cc;
  const unsigned short* pb = B + (size_t)(n0 + r0)*D + cc;
  for (int k0 = 0; k0 < D; k0 += 32){
    gload16(pa + k0,                 &Al[flat]);
    gload16(pa + (size_t)64*D + k0,  &Al[flat + 2048]);
    gload16(pb + k0,                 &Bl[flat]);
    gload16(pb + (size_t)64*D + k0,  &Bl[flat + 2048]);
    __syncthreads();
    int arow = (wr << 6) | (lane & 15);
    int brow = (wc << 6) | (lane & 15);
    int kg   = (lane >> 4) << 3;
    bf16x8 af[4], bfr[4];
    #pragma unroll
    for (int mi=0; mi<4; mi++) af[mi]  = *(const bf16x8*)&Al[(arow + (mi<<4))*32 + kg];
    #pragma unroll
    for (int ni=0; ni<4; ni++) bfr[ni] = *(const bf16x8*)&Bl[(brow + (ni<<4))*32 + kg];
    #pragma unroll
    for (int mi=0; mi<4; mi++)
      #pragma unroll
      for (int ni=0; ni<4; ni++)
        acc[mi][ni] = __builtin_amdgcn_mfma_f32_16x16x32_bf16(af[mi], bfr[ni], acc[mi][ni], 0, 0, 0);
    __syncthreads();
  }
  int crow = m0 + (wr << 6) + ((lane >> 4) << 2);
  int ccol = n0 + (wc << 6) + (lane & 15);
  #pragma unroll
  for (int mi=0; mi<4; mi++){
    #pragma unroll
    for (int q=0; q<4; q++){
      int row = crow + (mi << 4) + q;
      #pragma unroll
      for (int ni=0; ni<4; ni++){
        float val = acc[mi][ni][q] + bias[ccol + (ni << 4)];
        if (OUT_BF16)
          ((unsigned short*)Cv)[(size_t)row*D + ccol + (ni << 4)] = (unsigned short)f2bf(val);
        else
          ((float*)Cv)[(size_t)row*D + ccol + (ni << 4)] = val;
      }
    }
  }
}

// ---------------- LayerNorm + ReLU + subtract hist1[sid1] -> bf16 (y in bf16) ----------------
__global__ __launch_bounds__(256) void k_ln_relu_sub(
    const unsigned short* __restrict__ y, const float* __restrict__ gam, const float* __restrict__ bet,
    const float* __restrict__ hist1, const int* __restrict__ sid1,
    unsigned short* __restrict__ out)
{
  __shared__ float sh[8];
  int row = blockIdx.x, t = threadIdx.x;
  int c = t << 1;
  unsigned pv = *(const unsigned*)(y + (size_t)row*D + c);
  float vx = bf2f(pv & 0xffffu), vy = bf2f(pv >> 16);
  float s = vx + vy, ss = vx*vx + vy*vy;
  #pragma unroll
  for (int m=1; m<64; m<<=1){ s += __shfl_xor(s, m); ss += __shfl_xor(ss, m); }
  int wave = t >> 6, lane = t & 63;
  if (lane == 0){ sh[wave] = s; sh[4+wave] = ss; }
  __syncthreads();
  s  = sh[0]+sh[1]+sh[2]+sh[3];
  ss = sh[4]+sh[5]+sh[6]+sh[7];
  float mu  = s * (1.f/D);
  float var = ss * (1.f/D) - mu*mu;
  float rr  = rsqrtf(var + 1e-5f);
  int srow = sid1[row];
  float2 hv = *(const float2*)(hist1 + (size_t)srow*D + c);
  float o0 = fmaxf((vx - mu)*rr*gam[c]   + bet[c],   0.f) - hv.x;
  float o1 = fmaxf((vy - mu)*rr*gam[c+1] + bet[c+1], 0.f) - hv.y;
  *(unsigned*)(out + (size_t)row*D + c) = f2bf(o0) | (f2bf(o1) << 16);
}

// ---------------- log_softmax rows ----------------
__global__ __launch_bounds__(256) void k_logsoftmax(const float* __restrict__ y, float* __restrict__ out){
  __shared__ float sh[8];
  int row = blockIdx.x, t = threadIdx.x;
  int c = t << 1;
  float2 v = *(const float2*)(y + (size_t)row*D + c);
  float m = fmaxf(v.x, v.y);
  #pragma unroll
  for (int k=1; k<64; k<<=1) m = fmaxf(m, __shfl_xor(m, k));
  int wave = t >> 6, lane = t & 63;
  if (lane == 0) sh[wave] = m;
  __syncthreads();
  m = fmaxf(fmaxf(sh[0], sh[1]), fmaxf(sh[2], sh[3]));
  __syncthreads();
  float e = expf(v.x - m) + expf(v.y - m);
  #pragma unroll
  for (int k=1; k<64; k<<=1) e += __shfl_xor(e, k);
  if (lane == 0) sh[4+wave] = e;
  __syncthreads();
  e = sh[4]+sh[5]+sh[6]+sh[7];
  float lse = m + logf(e);
  float2 o; o.x = v.x - lse; o.y = v.y - lse;
  *(float2*)(out + (size_t)row*D + c) = o;
}

extern "C" void kernel_launch(void* const* d_in, const int* in_sizes, int n_in,
                              void* d_out, int out_size, void* d_ws, size_t ws_size,
                              hipStream_t stream)
{
  const float* x     = (const float*)d_in[0];
  const float* hist0 = (const float*)d_in[1];
  const float* hist1 = (const float*)d_in[2];
  const float* w0    = (const float*)d_in[3];
  const float* b0    = (const float*)d_in[4];
  const float* g0    = (const float*)d_in[5];
  const float* beta0 = (const float*)d_in[6];
  const float* w1    = (const float*)d_in[7];
  const float* b1    = (const float*)d_in[8];
  const float* s0v   = (const float*)d_in[9];
  const float* s1v   = (const float*)d_in[10];
  const float* f0v   = (const float*)d_in[11];
  const float* f1v   = (const float*)d_in[12];
  const int* sid0    = (const int*)d_in[13];
  const int* sid1    = (const int*)d_in[14];
  const int* fid0    = (const int*)d_in[16];
  const int* fid1    = (const int*)d_in[17];
  const int* s0r     = (const int*)d_in[18];
  const int* s0c     = (const int*)d_in[19];
  const int* s1r     = (const int*)d_in[20];
  const int* s1c     = (const int*)d_in[21];
  const int* f0r     = (const int*)d_in[22];
  const int* f0c     = (const int*)d_in[23];
  const int* f1r     = (const int*)d_in[24];
  const int* f1c     = (const int*)d_in[25];

  const int N  = 100000;
  const int N0 = 131072, N1 = 32768, N2 = 8192;
  const int Es0 = 262144, Es1 = 65536, Ef0 = 1048576, Ef1 = 262144;

  char* ws = (char*)d_ws;
  size_t off = 0;
  auto alloc = [&](size_t bytes)->char*{
    char* p = ws + off; off += (bytes + 255) & ~(size_t)255; return p;
  };
  char* regA = alloc((size_t)N0*D*2);      // 128MiB: h0 -> y1(bf16 32MB @0) + y2(f32 16MB @+64MiB)
  char* regH = alloc((size_t)N*D*2);       // 102MB : H0b -> g1buf (@0) + h1 (@+N1*D*2)
  char* regC = alloc((size_t)N1*D*2);      // 32MiB : out1 -> out2
  unsigned short* w0b = (unsigned short*)alloc((size_t)D*D*2);
  unsigned short* w1b = (unsigned short*)alloc((size_t)D*D*2);
  int* meta = (int*)alloc((size_t)(4*N1 + 4*N2)*4);
  int* cnt_s0 = meta;            int* fill_s0 = cnt_s0 + N1;
  int* cnt_f0 = fill_s0 + N1;    int* fill_f0 = cnt_f0 + N1;
  int* cnt_s1 = fill_f0 + N1;    int* fill_s1 = cnt_s1 + N2;
  int* cnt_f1 = fill_s1 + N2;    int* fill_f1 = cnt_f1 + N2;
  size_t metaBytes = (size_t)(4*N1 + 4*N2)*4;
  int* rp_s0 = (int*)alloc((size_t)(N1+1)*4);
  int* rp_f0 = (int*)alloc((size_t)(N1+1)*4);
  int* rp_s1 = (int*)alloc((size_t)(N2+1)*4);
  int* rp_f1 = (int*)alloc((size_t)(N2+1)*4);
  int2* bce_s0 = (int2*)alloc((size_t)Es0*8);
  int2* bce_f0 = (int2*)alloc((size_t)Ef0*8);
  int2* bce_s1 = (int2*)alloc((size_t)Es1*8);
  int2* bce_f1 = (int2*)alloc((size_t)Ef1*8);

  unsigned short* h0    = (unsigned short*)regA;
  unsigned short* y1    = (unsigned short*)regA;             // bf16, after spmm0 (h0 dead)
  float*          y2    = (float*)(regA + ((size_t)64<<20));
  unsigned short* H0b   = (unsigned short*)regH;
  unsigned short* g1buf = (unsigned short*)regH;             // after spmm0 (H0b dead)
  unsigned short* h1    = (unsigned short*)(regH + (size_t)N1*D*2);
  unsigned short* out1  = (unsigned short*)regC;
  unsigned short* out2  = (unsigned short*)regC;             // after gemm0 (out1 dead)
  float*          outp  = (float*)d_out;

  hipMemsetAsync(meta, 0, metaBytes, stream);
  k_f2bw<<<(2*D*D + 255)/256, 256, 0, stream>>>(w0, w1, w0b, w1b);
  // CSR build (f0 cols remapped through fid0 -> hist0 row ids)
  const int Etot = Es0 + Ef0 + Es1 + Ef1;
  k_count4<<<Etot/256, 256, 0, stream>>>(s0r, Es0, cnt_s0, f0r, Ef0, cnt_f0,
                                         s1r, Es1, cnt_s1, f1r, Ef1, cnt_f1);
  k_exscan4<<<4, 1024, 0, stream>>>(cnt_s0, rp_s0, N1, cnt_f0, rp_f0, N1,
                                    cnt_s1, rp_s1, N2, cnt_f1, rp_f1, N2);
  k_fill4<<<Etot/256, 256, 0, stream>>>(
      s0r, s0c, s0v, nullptr, rp_s0, fill_s0, bce_s0, Es0,
      f0r, f0c, f0v, fid0,    rp_f0, fill_f0, bce_f0, Ef0,
      s1r, s1c, s1v, nullptr, rp_s1, fill_s1, bce_s1, Es1,
      f1r, f1c, f1v, nullptr, rp_f1, fill_f1, bce_f1, Ef1);
  // hist0 -> bf16 table
  k_f2b8<<<(N*D/8 + 255)/256, 256, 0, stream>>>(hist0, H0b, N*D/8);
  // h0 = x[sid0] - H0b[sid0]  (bf16)
  k_gather_sub_mixed<<<N0*128/256, 256, 0, stream>>>(x, H0b, sid0, h0, N0);
  // layer 0 aggregation: fused s+f, wave-per-row
  k_spmm_dual<<<N1/4, 256, 0, stream>>>(rp_s0, bce_s0, h0, rp_f0, bce_f0, H0b, out1, N1);
  // layer-1 history pre-gather (H0b dead; reuse regH)
  k_gather1_bf16<<<N1*128/256, 256, 0, stream>>>(hist1, fid1, g1buf, N1);
  // dense + norm (y1 stored bf16)
  k_gemm_bias<true><<<(N1/128)*4, 256, 0, stream>>>(out1, w0b, b0, (void*)y1, N1);
  k_ln_relu_sub<<<N1, 256, 0, stream>>>(y1, g0, beta0, hist1, sid1, h1);
  // layer 1 aggregation
  k_spmm_dual<<<N2/4, 256, 0, stream>>>(rp_s1, bce_s1, h1, rp_f1, bce_f1, g1buf, out2, N2);
  // dense + log-softmax (y2 f32)
  k_gemm_bias<false><<<(N2/128)*4, 256, 0, stream>>>(out2, w1b, b1, (void*)y2, N2);
  k_logsoftmax<<<N2, 256, 0, stream>>>(y2, outp);
}